// Round 10
// baseline (359.699 us; speedup 1.0000x reference)
//
#include <hip/hip_runtime.h>
#include <math.h>

#define N_ENTC 30000
#define ALL_RELC 221
#define NDIM 32
#define EVAL_RELC 86
#define BB 16
#define NE 120000
#define NSCAN 120          /* scan blocks; NSCAN*EPB == NE */
#define EPB 1000
#define MW 938             /* bitmask words for 30000 entities */
#define CAPL 128           /* LDS compact-list capacity per list */

// K1: pure scan. Classify edges into 4 per-stripe record lists (R7-proven
// packed int4 format) + per-stripe counts; block 0 computes relw -> global.
// No zeroing, no messages, no fences. K2 sees everything via the dispatch
// boundary.
__global__ __launch_bounds__(512) void k_scan(
    const int* __restrict__ head, const int* __restrict__ tail,
    const int* __restrict__ eh, const int* __restrict__ et,
    const int* __restrict__ er, const float* __restrict__ ew,
    const float* __restrict__ ent_emb,
    const float* __restrict__ Wrel, const float* __restrict__ brel,
    const float* __restrict__ Watt, const float* __restrict__ batt,
    int4* __restrict__ recs, int* __restrict__ counts,
    float* __restrict__ relwG)
{
    __shared__ unsigned mH[MW], mT[MW];
    __shared__ int s_src[32];
    __shared__ int s_cnt[4];
    __shared__ float s_ht[BB * 64];
    __shared__ float s_h5[BB * 5];
    const int t = threadIdx.x, bid = blockIdx.x;

    if (t < 32) s_src[t] = (t < BB) ? head[t] : tail[t - BB];
    for (int i = t; i < MW; i += 512) { mH[i] = 0u; mT[i] = 0u; }
    if (t < 4) s_cnt[t] = 0;
    __syncthreads();
    if (t < BB) {
        int h = s_src[t], q = s_src[BB + t];
        atomicOr(&mH[h >> 5], 1u << (h & 31));
        atomicOr(&mT[q >> 5], 1u << (q & 31));
    }
    __syncthreads();

    const int e0 = bid * EPB;
    const int4* eh4 = (const int4*)(eh + e0);
    const int4* et4 = (const int4*)(et + e0);
    for (int p = t; p < EPB / 4; p += 512) {
        int4 h4 = eh4[p], t4 = et4[p];
        int hv[4] = {h4.x, h4.y, h4.z, h4.w};
        int tv[4] = {t4.x, t4.y, t4.z, t4.w};
#pragma unroll
        for (int c = 0; c < 4; c++) {
            int e = e0 + 4 * p + c, h = hv[c], tt = tv[c];
            bool hH = (mH[h >> 5] >> (h & 31)) & 1u;
            bool hT = (mT[h >> 5] >> (h & 31)) & 1u;
            bool tT = (mT[tt >> 5] >> (tt & 31)) & 1u;
            bool tH = (mH[tt >> 5] >> (tt & 31)) & 1u;
            if (!(hH | hT | tT | tH)) continue;
            int r = er[e];
            int wb = __float_as_int(ew[e]);
            if (hH) { // d=0 layer-1: srcmask over head ids
                unsigned m = 0;
#pragma unroll
                for (int b = 0; b < BB; b++) m |= (s_src[b] == h) ? (1u << b) : 0u;
                int pos = atomicAdd(&s_cnt[0], 1);
                recs[(size_t)bid * EPB + pos] = make_int4(tt, r | (int)(m << 8), wb, h);
            }
            if (hT) { // d=1 layer-1: srcmask over tail ids
                unsigned m = 0;
#pragma unroll
                for (int b = 0; b < BB; b++) m |= (s_src[BB + b] == h) ? (1u << b) : 0u;
                int pos = atomicAdd(&s_cnt[1], 1);
                recs[(size_t)NE + bid * EPB + pos] = make_int4(tt, r | (int)(m << 8), wb, h);
            }
            if (tT) { // d=0 layer-2: canon = first matching tail slot
                unsigned m = 0;
#pragma unroll
                for (int b = 0; b < BB; b++) m |= (s_src[BB + b] == tt) ? (1u << b) : 0u;
                int canon = __ffs(m) - 1;
                int pos = atomicAdd(&s_cnt[2], 1);
                recs[(size_t)2 * NE + bid * EPB + pos] = make_int4(h, r | (canon << 8), wb, tt);
            }
            if (tH) { // d=1 layer-2: canon = first matching head slot
                unsigned m = 0;
#pragma unroll
                for (int b = 0; b < BB; b++) m |= (s_src[b] == tt) ? (1u << b) : 0u;
                int canon = __ffs(m) - 1;
                int pos = atomicAdd(&s_cnt[3], 1);
                recs[(size_t)3 * NE + bid * EPB + pos] = make_int4(h, r | (canon << 8), wb, tt);
            }
        }
    }
    __syncthreads();
    if (t < 4) counts[bid * 4 + t] = s_cnt[t];

    if (bid == 0) { // relation-attention weights -> global (R7-proven math)
        for (int i = t; i < BB * NDIM; i += 512) {
            int b = i >> 5, k = i & 31;
            s_ht[b * 64 + k] = ent_emb[(size_t)s_src[b] * NDIM + k];
            s_ht[b * 64 + 32 + k] = ent_emb[(size_t)s_src[BB + b] * NDIM + k];
        }
        __syncthreads();
        for (int l = 0; l < 2; l++) {
            for (int i = t; i < BB * 5; i += 512) {
                int b = i / 5, j = i % 5;
                float s = brel[l * 5 + j];
                for (int k = 0; k < 64; k++)
                    s += s_ht[b * 64 + k] * Wrel[l * 320 + k * 5 + j];
                s_h5[i] = fmaxf(s, 0.f);
            }
            __syncthreads();
            for (int i = t; i < BB * ALL_RELC; i += 512) {
                int b = i / ALL_RELC, r = i % ALL_RELC;
                float s = batt[l * ALL_RELC + r];
                for (int j = 0; j < 5; j++)
                    s += s_h5[b * 5 + j] * Watt[l * 5 * ALL_RELC + j * ALL_RELC + r];
                relwG[l * BB * ALL_RELC + i] = 1.0f / (1.0f + expf(-s));
            }
            __syncthreads();
        }
    }
}

// K2: single block, 256 threads (4 waves). Compacts the 4 record lists into
// LDS (prefix-sum; global overflow keeps correctness for any input), then per
// direction: per L2 record a wave GATHERS its head's layer-1 message sum from
// the L1 list (register-accumulated, sources = s_ht), applies lin0+relu via
// the wave-tile (R8-proven), scatters layer-2 messages into LDS qacc (LDS
// atomics), then layer-2 linear + fin GEMM. No global sync anywhere.
__global__ __launch_bounds__(256) void k_all(
    const int* __restrict__ head, const int* __restrict__ tail,
    const float* __restrict__ ent_emb, const float* __restrict__ rel_embs,
    const float* __restrict__ Wlin, const float* __restrict__ blin,
    const float* __restrict__ Wr, const float* __restrict__ br,
    const int4* __restrict__ recs, const int* __restrict__ counts,
    const float* __restrict__ relwG, int4* __restrict__ gcomp,
    float* __restrict__ out)
{
    __shared__ float qacc[BB * 512];     // 32 KB; reused as sx in fin
    __shared__ float tiles[4][512];      // 8 KB per-wave lin tiles
    __shared__ int4 s_l[4][CAPL];        // 8 KB compact lists (L1d0,L1d1,L2d0,L2d1)
    __shared__ float s_ht[BB * 64];      // 4 KB
    __shared__ float sW[NDIM * NDIM];    // 4 KB (W0 then W1)
    __shared__ float sb_[NDIM];
    __shared__ int s_src[32];
    __shared__ int s_pref[4][128];       // 2 KB
    __shared__ int s_n[4];
    __shared__ float s_res[2][512];      // 4 KB: [0]=tail_hid(d0) [1]=head_hid(d1)
    __shared__ int s_canon[2][BB];

    const int t = threadIdx.x;
    const int wid = t >> 6, lane = t & 63;

    if (t < 32) s_src[t] = (t < BB) ? head[t] : tail[t - BB];
    __syncthreads();
    // NOTE: 256 threads -> MUST loop (R9 bug: `if (t < 512)` left half
    // of s_ht uninitialized; samples 8-15 read garbage)
    for (int i = t; i < BB * NDIM; i += 256) {
        int b = i >> 5, k = i & 31;
        s_ht[b * 64 + k] = ent_emb[(size_t)s_src[b] * NDIM + k];
        s_ht[b * 64 + 32 + k] = ent_emb[(size_t)s_src[BB + b] * NDIM + k];
    }
    if (t < 2 * BB) {
        int d = t >> 4, b = t & 15;
        int q = s_src[(1 - d) * BB + b];
        int c = 0;
        for (int bb = 0; bb < BB; bb++)
            if (s_src[(1 - d) * BB + bb] == q) { c = bb; break; }
        s_canon[d][b] = c;
    }

    // ---- prefix-sum the per-stripe counts, 4 lists ----
    for (int li = 0; li < 4; li++) {
        for (int i = t; i < 128; i += 256)
            s_pref[li][i] = (i < NSCAN) ? counts[4 * i + li] : 0;
        __syncthreads();
        for (int st = 1; st < 128; st <<= 1) {
            int v = (t < 128 && t >= st) ? s_pref[li][t - st] : 0;
            __syncthreads();
            if (t < 128) s_pref[li][t] += v;
            __syncthreads();
        }
        if (t == 0) s_n[li] = s_pref[li][NSCAN - 1];
    }
    // ---- compact: LDS up to CAPL, global overflow beyond ----
    for (int li = 0; li < 4; li++) {
        const int4* src = recs + (size_t)li * NE;
        int4* gDst = gcomp + (size_t)li * NE;
        for (int i = t; i < NSCAN; i += 256) {
            int pe = s_pref[li][i];
            int c = pe - ((i == 0) ? 0 : s_pref[li][i - 1]);
            int off = pe - c;
            for (int k = 0; k < c; k++) {
                int4 v = src[(size_t)i * EPB + k];
                int p = off + k;
                if (p < CAPL) s_l[li][p] = v; else gDst[p - CAPL] = v;
            }
        }
    }
    __syncthreads();

    const float* rw0 = relwG;
    const float* rw1 = relwG + BB * ALL_RELC;
    const float* rel0 = rel_embs;
    const float* rel1 = rel_embs + (size_t)ALL_RELC * NDIM;

    for (int d = 0; d < 2; d++) {
        // zero qacc; load W0/b0
        for (int i = t; i < BB * 512; i += 256) qacc[i] = 0.f;
        for (int i = t; i < NDIM * NDIM; i += 256) sW[i] = Wlin[i];
        if (t < NDIM) sb_[t] = blin[t];
        __syncthreads();

        const int n1 = s_n[d], n2 = s_n[2 + d];
        const int4* l1l = s_l[d];
        const int4* g1 = gcomp + (size_t)d * NE;
        const int4* l2l = s_l[2 + d];
        const int4* g2 = gcomp + (size_t)(2 + d) * NE;
        float* tw = &tiles[wid][0];
        const int ba = lane >> 3, bbs = ba + 8, kq = lane & 7;
        const int b4 = lane >> 2, j0 = (lane & 3) * 8;

        for (int j2 = wid; j2 < n2; j2 += 4) {
            int4 rec2 = (j2 < CAPL) ? l2l[j2] : g2[j2 - CAPL];
            int hh = rec2.x, r2 = rec2.y & 255, canon = (rec2.y >> 8) & 15;
            float w2 = __int_as_float(rec2.z);
            // gather layer-1 message sum for head hh (register acc)
            float4 a0 = make_float4(0.f, 0.f, 0.f, 0.f);
            float4 a1 = make_float4(0.f, 0.f, 0.f, 0.f);
            for (int j1 = 0; j1 < n1; j1++) {
                int4 rec1 = (j1 < CAPL) ? l1l[j1] : g1[j1 - CAPL];
                if (rec1.x != hh) continue;
                int r1 = rec1.y & 255;
                unsigned msk = ((unsigned)rec1.y) >> 8;
                float w1 = __int_as_float(rec1.z);
                float4 rr = ((const float4*)rel0)[r1 * 8 + kq];
                if ((msk >> ba) & 1u) {
                    float cf = rw0[ba * ALL_RELC + r1] * w1;
                    float4 sv = *(const float4*)&s_ht[ba * 64 + d * 32 + kq * 4];
                    a0.x += sv.x * cf * rr.x; a0.y += sv.y * cf * rr.y;
                    a0.z += sv.z * cf * rr.z; a0.w += sv.w * cf * rr.w;
                }
                if ((msk >> bbs) & 1u) {
                    float cf = rw0[bbs * ALL_RELC + r1] * w1;
                    float4 sv = *(const float4*)&s_ht[bbs * 64 + d * 32 + kq * 4];
                    a1.x += sv.x * cf * rr.x; a1.y += sv.y * cf * rr.y;
                    a1.z += sv.z * cf * rr.z; a1.w += sv.w * cf * rr.w;
                }
            }
            *(float4*)&tw[lane * 4] = a0;
            *(float4*)&tw[(lane + 64) * 4] = a1;
            // lin0 + relu from wave tile (same-wave LDS, in-order)
            const float4* srcT = (const float4*)&tw[b4 * NDIM];
            float h32[NDIM];
#pragma unroll
            for (int q = 0; q < 8; q++) {
                float4 v = srcT[q];
                h32[q * 4 + 0] = v.x; h32[q * 4 + 1] = v.y;
                h32[q * 4 + 2] = v.z; h32[q * 4 + 3] = v.w;
            }
            float acc[8];
#pragma unroll
            for (int jj = 0; jj < 8; jj++) acc[jj] = sb_[j0 + jj];
#pragma unroll
            for (int k = 0; k < NDIM; k++) {
                float4 w0 = *(const float4*)&sW[k * NDIM + j0];
                float4 w1v = *(const float4*)&sW[k * NDIM + j0 + 4];
                float hk = h32[k];
                acc[0] += hk * w0.x; acc[1] += hk * w0.y;
                acc[2] += hk * w0.z; acc[3] += hk * w0.w;
                acc[4] += hk * w1v.x; acc[5] += hk * w1v.y;
                acc[6] += hk * w1v.z; acc[7] += hk * w1v.w;
            }
            // layer-2 message -> LDS qacc (canon slot)
            float cf2 = rw1[b4 * ALL_RELC + r2] * w2;
#pragma unroll
            for (int jj = 0; jj < 8; jj++) {
                float val = fmaxf(acc[jj], 0.f) * cf2 * rel1[r2 * NDIM + j0 + jj];
                atomicAdd(&qacc[canon * 512 + b4 * NDIM + j0 + jj], val);
            }
        }
        __syncthreads();
        // layer-2 linear on (canon(b), b) segments
        for (int i = t; i < NDIM * NDIM; i += 256) sW[i] = Wlin[NDIM * NDIM + i];
        if (t < NDIM) sb_[t] = blin[NDIM + t];
        __syncthreads();
        for (int i = t; i < 512; i += 256) {
            int b = i >> 5, j = i & 31;
            const float* hrow = &qacc[s_canon[d][b] * 512 + b * NDIM];
            float s = sb_[j];
            for (int k = 0; k < NDIM; k++)
                s += hrow[k] * sW[k * NDIM + j];
            s_res[d][i] = fmaxf(s, 0.f);
        }
        __syncthreads(); // qacc reused next iteration / as sx
    }

    // ---- fin: gather + 16x128 @ 128x86 ----
    float* sx = qacc; // [16][128] = hemb|temb|head_hid|tail_hid
    for (int i = t; i < 512; i += 256) {
        int b = i >> 5, k = i & 31;
        sx[b * 128 + k] = s_ht[b * 64 + k];
        sx[b * 128 + 32 + k] = s_ht[b * 64 + 32 + k];
        sx[b * 128 + 64 + k] = s_res[1][b * 32 + k]; // head_hid (d=1)
        sx[b * 128 + 96 + k] = s_res[0][b * 32 + k]; // tail_hid (d=0)
    }
    __syncthreads();
    for (int o = t; o < BB * EVAL_RELC; o += 256) {
        int b = o / EVAL_RELC, r = o % EVAL_RELC;
        float s = br[r];
        for (int k = 0; k < 128; k++)
            s += sx[b * 128 + k] * Wr[k * EVAL_RELC + r];
        out[o] = s;
    }
}

extern "C" void kernel_launch(void* const* d_in, const int* in_sizes, int n_in,
                              void* d_out, int out_size, void* d_ws,
                              size_t ws_size, hipStream_t stream)
{
    const int* head = (const int*)d_in[0];
    const int* tail = (const int*)d_in[1];
    const int* eh = (const int*)d_in[2];
    const int* et = (const int*)d_in[3];
    const int* er = (const int*)d_in[4];
    const float* ew = (const float*)d_in[5];
    const float* ent_emb = (const float*)d_in[6];
    const float* rel_embs = (const float*)d_in[7];
    const float* Wlin = (const float*)d_in[8];
    const float* blin = (const float*)d_in[9];
    const float* Wrel = (const float*)d_in[10];
    const float* brel = (const float*)d_in[11];
    const float* Watt = (const float*)d_in[12];
    const float* batt = (const float*)d_in[13];
    const float* Wr = (const float*)d_in[14];
    const float* br = (const float*)d_in[15];
    float* out = (float*)d_out;
    float* ws = (float*)d_ws;

    // ---- workspace carve (~15.4 MB) ----
    int4* recs = (int4*)ws;                              // [4][NE] int4
    int4* gcomp = recs + (size_t)4 * NE;                 // [4][NE] int4 overflow
    int* counts = (int*)(gcomp + (size_t)4 * NE);        // [NSCAN][4]
    float* relwG = (float*)(counts + 4 * NSCAN);         // 7072

    k_scan<<<NSCAN, 512, 0, stream>>>(head, tail, eh, et, er, ew, ent_emb,
                                      Wrel, brel, Watt, batt,
                                      recs, counts, relwG);
    k_all<<<1, 256, 0, stream>>>(head, tail, ent_emb, rel_embs, Wlin, blin,
                                 Wr, br, recs, counts, relwG, gcomp, out);
}

// Round 11
// 125.810 us; speedup vs baseline: 2.8591x; 2.8591x over previous
//
#include <hip/hip_runtime.h>
#include <math.h>

#define N_ENTC 30000
#define ALL_RELC 221
#define NDIM 32
#define EVAL_RELC 86
#define BB 16
#define NE 120000
#define ROW 512            /* BB*NDIM floats per qacc row */
#define NSCAN 120          /* scan blocks; NSCAN*EPB == NE */
#define EPB 1000
#define MW 938             /* bitmask words for 30000 entities */
#define CAPL2 512          /* LDS L1-list capacity per direction (k_mid) */

// K1: pure scan (R10-proven). Per-stripe record lists + counts; block 0
// computes relw -> global; block 1 zeroes global qacc. No fences.
__global__ __launch_bounds__(512) void k_scan(
    const int* __restrict__ head, const int* __restrict__ tail,
    const int* __restrict__ eh, const int* __restrict__ et,
    const int* __restrict__ er, const float* __restrict__ ew,
    const float* __restrict__ ent_emb,
    const float* __restrict__ Wrel, const float* __restrict__ brel,
    const float* __restrict__ Watt, const float* __restrict__ batt,
    int4* __restrict__ recs, int* __restrict__ counts,
    float* __restrict__ relwG, float* __restrict__ qaccB)
{
    __shared__ unsigned mH[MW], mT[MW];
    __shared__ int s_src[32];
    __shared__ int s_cnt[4];
    __shared__ float s_ht[BB * 64];
    __shared__ float s_h5[BB * 5];
    const int t = threadIdx.x, bid = blockIdx.x;

    if (t < 32) s_src[t] = (t < BB) ? head[t] : tail[t - BB];
    for (int i = t; i < MW; i += 512) { mH[i] = 0u; mT[i] = 0u; }
    if (t < 4) s_cnt[t] = 0;
    __syncthreads();
    if (t < BB) {
        int h = s_src[t], q = s_src[BB + t];
        atomicOr(&mH[h >> 5], 1u << (h & 31));
        atomicOr(&mT[q >> 5], 1u << (q & 31));
    }
    __syncthreads();

    const int e0 = bid * EPB;
    const int4* eh4 = (const int4*)(eh + e0);
    const int4* et4 = (const int4*)(et + e0);
    for (int p = t; p < EPB / 4; p += 512) {
        int4 h4 = eh4[p], t4 = et4[p];
        int hv[4] = {h4.x, h4.y, h4.z, h4.w};
        int tv[4] = {t4.x, t4.y, t4.z, t4.w};
#pragma unroll
        for (int c = 0; c < 4; c++) {
            int e = e0 + 4 * p + c, h = hv[c], tt = tv[c];
            bool hH = (mH[h >> 5] >> (h & 31)) & 1u;
            bool hT = (mT[h >> 5] >> (h & 31)) & 1u;
            bool tT = (mT[tt >> 5] >> (tt & 31)) & 1u;
            bool tH = (mH[tt >> 5] >> (tt & 31)) & 1u;
            if (!(hH | hT | tT | tH)) continue;
            int r = er[e];
            int wb = __float_as_int(ew[e]);
            if (hH) { // d=0 layer-1: srcmask over head ids
                unsigned m = 0;
#pragma unroll
                for (int b = 0; b < BB; b++) m |= (s_src[b] == h) ? (1u << b) : 0u;
                int pos = atomicAdd(&s_cnt[0], 1);
                recs[(size_t)bid * EPB + pos] = make_int4(tt, r | (int)(m << 8), wb, h);
            }
            if (hT) { // d=1 layer-1: srcmask over tail ids
                unsigned m = 0;
#pragma unroll
                for (int b = 0; b < BB; b++) m |= (s_src[BB + b] == h) ? (1u << b) : 0u;
                int pos = atomicAdd(&s_cnt[1], 1);
                recs[(size_t)NE + bid * EPB + pos] = make_int4(tt, r | (int)(m << 8), wb, h);
            }
            if (tT) { // d=0 layer-2: canon = first matching tail slot
                unsigned m = 0;
#pragma unroll
                for (int b = 0; b < BB; b++) m |= (s_src[BB + b] == tt) ? (1u << b) : 0u;
                int canon = __ffs(m) - 1;
                int pos = atomicAdd(&s_cnt[2], 1);
                recs[(size_t)2 * NE + bid * EPB + pos] = make_int4(h, r | (canon << 8), wb, tt);
            }
            if (tH) { // d=1 layer-2: canon = first matching head slot
                unsigned m = 0;
#pragma unroll
                for (int b = 0; b < BB; b++) m |= (s_src[b] == tt) ? (1u << b) : 0u;
                int canon = __ffs(m) - 1;
                int pos = atomicAdd(&s_cnt[3], 1);
                recs[(size_t)3 * NE + bid * EPB + pos] = make_int4(h, r | (canon << 8), wb, tt);
            }
        }
    }
    __syncthreads();
    if (t < 4) counts[bid * 4 + t] = s_cnt[t];

    if (bid == 1) { // zero global qacc (both directions)
        for (int i = t; i < 2 * BB * ROW; i += 512) qaccB[i] = 0.f;
    }
    if (bid == 0) { // relation-attention weights -> global (R7-proven math)
        for (int i = t; i < BB * NDIM; i += 512) {
            int b = i >> 5, k = i & 31;
            s_ht[b * 64 + k] = ent_emb[(size_t)s_src[b] * NDIM + k];
            s_ht[b * 64 + 32 + k] = ent_emb[(size_t)s_src[BB + b] * NDIM + k];
        }
        __syncthreads();
        for (int l = 0; l < 2; l++) {
            for (int i = t; i < BB * 5; i += 512) {
                int b = i / 5, j = i % 5;
                float s = brel[l * 5 + j];
                for (int k = 0; k < 64; k++)
                    s += s_ht[b * 64 + k] * Wrel[l * 320 + k * 5 + j];
                s_h5[i] = fmaxf(s, 0.f);
            }
            __syncthreads();
            for (int i = t; i < BB * ALL_RELC; i += 512) {
                int b = i / ALL_RELC, r = i % ALL_RELC;
                float s = batt[l * ALL_RELC + r];
                for (int j = 0; j < 5; j++)
                    s += s_h5[b * 5 + j] * Watt[l * 5 * ALL_RELC + j * ALL_RELC + r];
                relwG[l * BB * ALL_RELC + i] = 1.0f / (1.0f + expf(-s));
            }
            __syncthreads();
        }
    }
}

// K2: 120 blocks x 256. Block bid handles its OWN stripe's L2 records.
// Stages the full L1 lists (both dirs) into LDS, then per L2 record a wave:
// gathers the head's layer-1 sum from LDS (R10-proven), lin0+relu via the
// wave tile (R8-proven), scatters layer-2 messages into GLOBAL qacc
// (R7-proven volume). Fallback to global L1 scan if a list exceeds CAPL2.
__global__ __launch_bounds__(256) void k_mid(
    const int* __restrict__ head, const int* __restrict__ tail,
    const float* __restrict__ ent_emb, const float* __restrict__ rel_embs,
    const float* __restrict__ Wlin, const float* __restrict__ blin,
    const int4* __restrict__ recs, const int* __restrict__ counts,
    const float* __restrict__ relwG, float* __restrict__ qaccB)
{
    __shared__ int4 s_l1[2][CAPL2];   // 16 KB
    __shared__ float tiles[4][512];   // 8 KB per-wave lin tiles
    __shared__ float s_ht[BB * 64];   // 4 KB
    __shared__ float sW[NDIM * NDIM]; // 4 KB (layer 0)
    __shared__ float sb_[NDIM];
    __shared__ int s_src[32];
    __shared__ int s_n1[2];
    __shared__ int s_ovf;

    const int t = threadIdx.x, bid = blockIdx.x;
    int4 c4 = ((const int4*)counts)[bid];
    if ((c4.z | c4.w) == 0) return; // no L2 records in this stripe

    if (t < 32) s_src[t] = (t < BB) ? head[t] : tail[t - BB];
    if (t == 0) { s_n1[0] = 0; s_n1[1] = 0; s_ovf = 0; }
    for (int i = t; i < NDIM * NDIM; i += 256) sW[i] = Wlin[i];
    if (t < NDIM) sb_[t] = blin[t];
    __syncthreads();
    // s_ht: MUST loop with 256 threads (R9 lesson)
    for (int i = t; i < BB * NDIM; i += 256) {
        int b = i >> 5, k = i & 31;
        s_ht[b * 64 + k] = ent_emb[(size_t)s_src[b] * NDIM + k];
        s_ht[b * 64 + 32 + k] = ent_emb[(size_t)s_src[BB + b] * NDIM + k];
    }
    // stage L1 lists (order irrelevant for a gather-sum)
    for (int d = 0; d < 2; d++) {
        for (int i = t; i < NSCAN; i += 256) {
            int c = counts[4 * i + d];
            if (!c) continue;
            int pos = atomicAdd(&s_n1[d], c);
            if (pos + c > CAPL2) { atomicOr(&s_ovf, 1 << d); continue; }
            for (int k = 0; k < c; k++)
                s_l1[d][pos + k] = recs[(size_t)d * NE + (size_t)i * EPB + k];
        }
    }
    __syncthreads();

    const int wid = t >> 6, lane = t & 63;
    const float* rw0 = relwG;
    const float* rw1 = relwG + BB * ALL_RELC;
    const float4* rel0 = (const float4*)rel_embs;
    const float* rel1 = rel_embs + (size_t)ALL_RELC * NDIM;
    const int ba = lane >> 3, bbs = ba + 8, kq = lane & 7;
    const int b4 = lane >> 2, j0 = (lane & 3) * 8;
    float* tw = &tiles[wid][0];

    for (int d = 0; d < 2; d++) {
        int n2 = d ? c4.w : c4.z;
        const int4* R2 = recs + (size_t)(2 + d) * NE + (size_t)bid * EPB;
        const bool ovf = (s_ovf >> d) & 1;
        const int n1 = s_n1[d];
        float* qa = qaccB + (size_t)d * BB * ROW;
        for (int j2 = wid; j2 < n2; j2 += 4) {
            int4 rec2 = R2[j2];
            int hh = rec2.x, r2 = rec2.y & 255, canon = (rec2.y >> 8) & 15;
            float w2 = __int_as_float(rec2.z);
            // ---- gather layer-1 sum for head hh (R10-proven math) ----
            float4 a0 = make_float4(0.f, 0.f, 0.f, 0.f);
            float4 a1 = make_float4(0.f, 0.f, 0.f, 0.f);
            if (!ovf) {
                for (int j1 = 0; j1 < n1; j1++) {
                    int4 rec1 = s_l1[d][j1];
                    if (rec1.x != hh) continue;
                    int r1 = rec1.y & 255;
                    unsigned msk = ((unsigned)rec1.y) >> 8;
                    float w1 = __int_as_float(rec1.z);
                    float4 rr = rel0[r1 * 8 + kq];
                    if ((msk >> ba) & 1u) {
                        float cf = rw0[ba * ALL_RELC + r1] * w1;
                        float4 sv = *(const float4*)&s_ht[ba * 64 + d * 32 + kq * 4];
                        a0.x += sv.x * cf * rr.x; a0.y += sv.y * cf * rr.y;
                        a0.z += sv.z * cf * rr.z; a0.w += sv.w * cf * rr.w;
                    }
                    if ((msk >> bbs) & 1u) {
                        float cf = rw0[bbs * ALL_RELC + r1] * w1;
                        float4 sv = *(const float4*)&s_ht[bbs * 64 + d * 32 + kq * 4];
                        a1.x += sv.x * cf * rr.x; a1.y += sv.y * cf * rr.y;
                        a1.z += sv.z * cf * rr.z; a1.w += sv.w * cf * rr.w;
                    }
                }
            } else { // correct-but-slow fallback: scan global per-stripe lists
                for (int s = 0; s < NSCAN; s++) {
                    int c = counts[4 * s + d];
                    for (int k = 0; k < c; k++) {
                        int4 rec1 = recs[(size_t)d * NE + (size_t)s * EPB + k];
                        if (rec1.x != hh) continue;
                        int r1 = rec1.y & 255;
                        unsigned msk = ((unsigned)rec1.y) >> 8;
                        float w1 = __int_as_float(rec1.z);
                        float4 rr = rel0[r1 * 8 + kq];
                        if ((msk >> ba) & 1u) {
                            float cf = rw0[ba * ALL_RELC + r1] * w1;
                            float4 sv = *(const float4*)&s_ht[ba * 64 + d * 32 + kq * 4];
                            a0.x += sv.x * cf * rr.x; a0.y += sv.y * cf * rr.y;
                            a0.z += sv.z * cf * rr.z; a0.w += sv.w * cf * rr.w;
                        }
                        if ((msk >> bbs) & 1u) {
                            float cf = rw0[bbs * ALL_RELC + r1] * w1;
                            float4 sv = *(const float4*)&s_ht[bbs * 64 + d * 32 + kq * 4];
                            a1.x += sv.x * cf * rr.x; a1.y += sv.y * cf * rr.y;
                            a1.z += sv.z * cf * rr.z; a1.w += sv.w * cf * rr.w;
                        }
                    }
                }
            }
            // tile layout: [b][32 dims] row-major (R10-proven)
            *(float4*)&tw[lane * 4] = a0;
            *(float4*)&tw[(lane + 64) * 4] = a1;
            // ---- lin0 from wave tile (same-wave LDS, in-order; R8-proven) ----
            const float4* srcT = (const float4*)&tw[b4 * NDIM];
            float h32[NDIM];
#pragma unroll
            for (int q = 0; q < 8; q++) {
                float4 v = srcT[q];
                h32[q * 4 + 0] = v.x; h32[q * 4 + 1] = v.y;
                h32[q * 4 + 2] = v.z; h32[q * 4 + 3] = v.w;
            }
            float acc[8];
#pragma unroll
            for (int jj = 0; jj < 8; jj++) acc[jj] = sb_[j0 + jj];
#pragma unroll
            for (int k = 0; k < NDIM; k++) {
                float4 w0 = *(const float4*)&sW[k * NDIM + j0];
                float4 w1v = *(const float4*)&sW[k * NDIM + j0 + 4];
                float hk = h32[k];
                acc[0] += hk * w0.x; acc[1] += hk * w0.y;
                acc[2] += hk * w0.z; acc[3] += hk * w0.w;
                acc[4] += hk * w1v.x; acc[5] += hk * w1v.y;
                acc[6] += hk * w1v.z; acc[7] += hk * w1v.w;
            }
            // ---- layer-2 message -> global qacc (R7-proven volume) ----
            float cf2 = rw1[b4 * ALL_RELC + r2] * w2;
#pragma unroll
            for (int jj = 0; jj < 8; jj++) {
                float val = fmaxf(acc[jj], 0.f) * cf2 * rel1[r2 * NDIM + j0 + jj];
                atomicAdd(&qa[canon * ROW + b4 * NDIM + j0 + jj], val);
            }
        }
    }
}

// K3: fin (R7-proven, verbatim). Layer-2 linear on (canon,b) segments +
// gather + 16x128 @ 128x86 output GEMM. 1 block x 512.
__global__ __launch_bounds__(512) void k_fin(
    const int* __restrict__ head, const int* __restrict__ tail,
    const float* __restrict__ ent_emb, const float* __restrict__ Wlin,
    const float* __restrict__ blin, const float* __restrict__ Wr,
    const float* __restrict__ br, const float* __restrict__ qaccB,
    float* __restrict__ out)
{
    __shared__ float sx[BB * 128]; // hemb|temb|head_hid|tail_hid
    __shared__ float sW[NDIM * NDIM];
    __shared__ float sb[NDIM];
    __shared__ int s_src[32];
    __shared__ int s_canon[2][BB];
    const int t = threadIdx.x;

    if (t < 32) s_src[t] = (t < BB) ? head[t] : tail[t - BB];
    for (int i = t; i < NDIM * NDIM; i += 512) sW[i] = Wlin[NDIM * NDIM + i]; // layer 1
    if (t < NDIM) sb[t] = blin[NDIM + t];
    __syncthreads();
    if (t < 2 * BB) {
        int d = t >> 4, b = t & 15;
        int q = s_src[(1 - d) * BB + b];
        int c = 0;
        for (int bb = 0; bb < BB; bb++)
            if (s_src[(1 - d) * BB + bb] == q) { c = bb; break; }
        s_canon[d][b] = c;
    }
    {
        int b = t >> 5, k = t & 31;
        sx[b * 128 + k] = ent_emb[(size_t)s_src[b] * NDIM + k];           // hemb
        sx[b * 128 + 32 + k] = ent_emb[(size_t)s_src[BB + b] * NDIM + k]; // temb
    }
    __syncthreads();
    for (int d = 0; d < 2; d++) { // layer-2 linear on (canon,b) segments
        int b = t >> 5, j = t & 31;
        const float* hrow = qaccB + (size_t)d * BB * ROW + s_canon[d][b] * ROW + b * NDIM;
        float s = sb[j];
        for (int k = 0; k < NDIM; k++)
            s += hrow[k] * sW[k * NDIM + j];
        // d=0 (init=head, query=tail) -> tail_hid (col 96); d=1 -> head_hid (col 64)
        sx[b * 128 + (d == 0 ? 96 : 64) + j] = fmaxf(s, 0.f);
    }
    __syncthreads();
    for (int o = t; o < BB * EVAL_RELC; o += 512) {
        int b = o / EVAL_RELC, r = o % EVAL_RELC;
        float s = br[r];
        for (int k = 0; k < 128; k++)
            s += sx[b * 128 + k] * Wr[k * EVAL_RELC + r];
        out[o] = s;
    }
}

extern "C" void kernel_launch(void* const* d_in, const int* in_sizes, int n_in,
                              void* d_out, int out_size, void* d_ws,
                              size_t ws_size, hipStream_t stream)
{
    const int* head = (const int*)d_in[0];
    const int* tail = (const int*)d_in[1];
    const int* eh = (const int*)d_in[2];
    const int* et = (const int*)d_in[3];
    const int* er = (const int*)d_in[4];
    const float* ew = (const float*)d_in[5];
    const float* ent_emb = (const float*)d_in[6];
    const float* rel_embs = (const float*)d_in[7];
    const float* Wlin = (const float*)d_in[8];
    const float* blin = (const float*)d_in[9];
    const float* Wrel = (const float*)d_in[10];
    const float* brel = (const float*)d_in[11];
    const float* Watt = (const float*)d_in[12];
    const float* batt = (const float*)d_in[13];
    const float* Wr = (const float*)d_in[14];
    const float* br = (const float*)d_in[15];
    float* out = (float*)d_out;
    float* ws = (float*)d_ws;

    // ---- workspace carve (~7.8 MB) ----
    int4* recs = (int4*)ws;                              // [4][NE] int4
    int* counts = (int*)(recs + (size_t)4 * NE);         // [NSCAN][4]
    float* relwG = (float*)(counts + 4 * NSCAN);         // 7072
    float* qaccB = relwG + 7072;                         // [2][16][512]

    k_scan<<<NSCAN, 512, 0, stream>>>(head, tail, eh, et, er, ew, ent_emb,
                                      Wrel, brel, Watt, batt,
                                      recs, counts, relwG, qaccB);
    k_mid<<<NSCAN, 256, 0, stream>>>(head, tail, ent_emb, rel_embs,
                                     Wlin, blin, recs, counts, relwG, qaccB);
    k_fin<<<1, 512, 0, stream>>>(head, tail, ent_emb, Wlin, blin, Wr, br,
                                 qaccB, out);
}